// Round 3
// baseline (83.967 us; speedup 1.0000x reference)
//
#include <hip/hip_runtime.h>
#include <math.h>

#define W_POS 0.1f
#define W_SCALE 0.1f
#define W_ROT 0.1f
#define W_COLOR 0.1f

__device__ __forceinline__ unsigned umed3(unsigned a, unsigned b, unsigned c) {
    unsigned d;
    asm("v_med3_u32 %0, %1, %2, %3" : "=v"(d) : "v"(a), "v"(b), "v"(c));
    return d;
}
__device__ __forceinline__ unsigned umin_(unsigned a, unsigned b) {
    unsigned d;
    asm("v_min_u32 %0, %1, %2" : "=v"(d) : "v"(a), "v"(b));
    return d;
}

// Insert key into ascending sorted 7-list e0..e6 (drops current max).
// e_k = min(e_k, max(e_{k-1}, key)) == med3(key, e_{k-1}, e_k) since e_{k-1} <= e_k.
// All 7 med3 ops use OLD neighbor values -> mutually independent (good ILP).
#define INSERT7(keyv) do { unsigned _k = (keyv);  \
    e6 = umed3(_k, e5, e6);                       \
    e5 = umed3(_k, e4, e5);                       \
    e4 = umed3(_k, e3, e4);                       \
    e3 = umed3(_k, e2, e3);                       \
    e2 = umed3(_k, e1, e2);                       \
    e1 = umed3(_k, e0, e1);                       \
    e0 = umin_(e0, _k);  } while (0)

// Kernel 1: pack positions {x,y,z,|x|^2}, compute all elementwise loss terms
// (block-reduced into epart), and zero the sync counters for kernel 2.
__global__ __launch_bounds__(256) void prep_kernel(
    const float* __restrict__ pos,
    const float* __restrict__ scales,
    const float* __restrict__ rots,
    const float* __restrict__ colors,
    float4* __restrict__ packed,
    double* __restrict__ epart,
    unsigned* __restrict__ ctrg,   // [128 group ctrs][1 global ctr]
    int n)
{
    const int r = blockIdx.x * 256 + threadIdx.x;

    float x = pos[3 * r], y = pos[3 * r + 1], z = pos[3 * r + 2];
    packed[r] = make_float4(x, y, z, x * x + y * y + z * z);

    const float invn = 1.0f / (float)n;
    float s0 = scales[3 * r], s1 = scales[3 * r + 1], s2 = scales[3 * r + 2];
    float m = (s0 + s1 + s2) * (1.0f / 3.0f);
    float var = ((s0 - m) * (s0 - m) + (s1 - m) * (s1 - m) + (s2 - m) * (s2 - m)) * 0.5f;
    float al = fabsf(s0 - 1.0f) + fabsf(s1 - 1.0f) + fabsf(s2 - 1.0f);
    float r0 = rots[4 * r], r1 = rots[4 * r + 1], r2 = rots[4 * r + 2], r3 = rots[4 * r + 3];
    float nm = sqrtf(r0 * r0 + r1 * r1 + r2 * r2 + r3 * r3);
    float c0 = colors[3 * r], c1 = colors[3 * r + 1], c2 = colors[3 * r + 2];

    float contrib =
        W_SCALE * (al * (invn / 3.0f) + var * invn) +
        W_ROT * (nm - 1.0f) * (nm - 1.0f) * invn +
        W_COLOR * ((c0 - .5f) * (c0 - .5f) + (c1 - .5f) * (c1 - .5f) + (c2 - .5f) * (c2 - .5f)) * (invn / 3.0f);

    __shared__ double sm[256];
    sm[threadIdx.x] = (double)contrib;
    __syncthreads();
    for (int step = 128; step; step >>= 1) {
        if ((int)threadIdx.x < step) sm[threadIdx.x] += sm[threadIdx.x + step];
        __syncthreads();
    }
    if (threadIdx.x == 0) epart[blockIdx.x] = sm[0];

    if (blockIdx.x == 0 && threadIdx.x < 129) ctrg[threadIdx.x] = 0;
}

// Kernel 2: pass (lane owns a row, wave scans a uniform candidate chunk via
// scalar loads) + intra-block LDS merge + per-group global merge + epilogue +
// final reduction, chained with fence/atomic counters (device scope).
__global__ __launch_bounds__(256) void pass_kernel(
    const float4* __restrict__ packed,
    const float* __restrict__ colors,
    unsigned* __restrict__ lists,
    unsigned* __restrict__ ctrg,
    double* __restrict__ gpart,
    const double* __restrict__ epart,
    float* __restrict__ out, int n)
{
    const int lane = threadIdx.x & 63;
    const int wv = threadIdx.x >> 6;
    const int g = blockIdx.x;      // row group (64 rows)
    const int s = blockIdx.y;      // candidate super-chunk (16)
    const int row = g * 64 + lane;

    const float4 q = packed[row];
    const float sqi = q.w;
    const float qx2 = -2.0f * q.x, qy2 = -2.0f * q.y, qz2 = -2.0f * q.z;

    unsigned e0 = 0xFFFFFFFFu, e1 = 0xFFFFFFFFu, e2 = 0xFFFFFFFFu, e3 = 0xFFFFFFFFu,
             e4 = 0xFFFFFFFFu, e5 = 0xFFFFFFFFu, e6 = 0xFFFFFFFFu;

    // wave-uniform base -> SGPR; candidate loads become scalar loads
    const int base = __builtin_amdgcn_readfirstlane((s * 4 + wv) * 128);
#pragma unroll 8
    for (int t = 0; t < 128; ++t) {
        float4 p = packed[base + t];
        float c0 = fmaf(qz2, p.z, sqi);
        float c1 = fmaf(qy2, p.y, c0);
        float c2 = fmaf(qx2, p.x, c1);
        float d2 = fmaxf(c2 + p.w, 0.0f);
        // truncate low 13 mantissa bits, pack candidate index: order matches
        // top_k (distance asc, then smaller index)
        unsigned key = (__float_as_uint(d2) & 0xFFFFE000u) | (unsigned)(base + t);
        INSERT7(key);
    }

    // intra-block merge: waves 1..3 publish, wave 0 absorbs their 21 keys
    __shared__ unsigned sml[3][64][9];   // pad to 9 words: conflict-free
    if (wv > 0) {
        unsigned* p = sml[wv - 1][lane];
        p[0] = e0; p[1] = e1; p[2] = e2; p[3] = e3; p[4] = e4; p[5] = e5; p[6] = e6;
    }
    __syncthreads();
    if (wv != 0) return;

#pragma unroll
    for (int w = 0; w < 3; ++w) {
        unsigned* p = sml[w][lane];
        INSERT7(p[0]); INSERT7(p[1]); INSERT7(p[2]); INSERT7(p[3]);
        INSERT7(p[4]); INSERT7(p[5]); INSERT7(p[6]);
    }
    unsigned* dst = lists + (((size_t)s * n + row) << 3);
    *(uint4*)dst = make_uint4(e0, e1, e2, e3);
    *(uint4*)(dst + 4) = make_uint4(e4, e5, e6, 0xFFFFFFFFu);

    // release: publish this chunk's lists, bump the group's counter
    __threadfence();
    int old = 0;
    if (lane == 0) old = (int)atomicAdd(&ctrg[g], 1u);
    old = __shfl(old, 0, 64);
    if (old != 15) return;           // not the last chunk of this group

    // acquire, then merge the 16 sorted 7-lists for each of our 64 rows
    __threadfence();
    e0 = e1 = e2 = e3 = e4 = e5 = e6 = 0xFFFFFFFFu;
    for (int c = 0; c < 16; ++c) {
        const uint4* p4 = (const uint4*)(lists + (((size_t)c * n + row) << 3));
        uint4 a = p4[0], b = p4[1];
        INSERT7(a.x); INSERT7(a.y); INSERT7(a.z); INSERT7(a.w);
        INSERT7(b.x); INSERT7(b.y); INSERT7(b.z);
    }

    // self-exclusion (self may sit anywhere, or be absent if d2 rounded negative)
    const unsigned M = 0x1FFFu;
    int spos = ((e0 & M) == (unsigned)row) ? 0 :
               ((e1 & M) == (unsigned)row) ? 1 :
               ((e2 & M) == (unsigned)row) ? 2 :
               ((e3 & M) == (unsigned)row) ? 3 :
               ((e4 & M) == (unsigned)row) ? 4 :
               ((e5 & M) == (unsigned)row) ? 5 :
               ((e6 & M) == (unsigned)row) ? 6 : 7;
    unsigned u0 = (spos == 0) ? e1 : e0;
    unsigned u1 = (spos <= 1) ? e2 : e1;
    unsigned u2 = (spos <= 2) ? e3 : e2;
    unsigned u3 = (spos <= 3) ? e4 : e3;
    unsigned u4 = (spos <= 4) ? e5 : e4;

    // exact recompute of 2nd-NN distance (selection keys were truncated)
    const int i2 = (int)(u1 & M);
    const float4 p2 = packed[i2];
    float dot2 = fmaf(q.x, p2.x, fmaf(q.y, p2.y, q.z * p2.z));
    float d2e = fmaxf(q.w + p2.w - 2.0f * dot2, 0.0f);
    float min_d = sqrtf(d2e);

    // color smoothness over the 5 nearest off-diag neighbors
    float c0 = colors[3 * row], c1 = colors[3 * row + 1], c2 = colors[3 * row + 2];
    float cs = 0.0f;
    unsigned nb[5] = { u0, u1, u2, u3, u4 };
#pragma unroll
    for (int k = 0; k < 5; ++k) {
        int nidx = (int)(nb[k] & M);
        cs += fabsf(c0 - colors[3 * nidx]);
        cs += fabsf(c1 - colors[3 * nidx + 1]);
        cs += fabsf(c2 - colors[3 * nidx + 2]);
    }

    const float invn = 1.0f / (float)n;
    double contrib = (double)(cs * (W_COLOR * invn / 15.0f) + expf(-min_d) * (W_POS * invn));

    // deterministic 64-lane butterfly reduce (fixed tree)
#pragma unroll
    for (int off = 32; off; off >>= 1)
        contrib += __shfl_xor(contrib, off, 64);

    if (lane == 0) {
        gpart[g] = contrib;
        __threadfence();
        old = (int)atomicAdd(&ctrg[128], 1u);
    }
    old = __shfl(old, 0, 64);
    if (old != 127) return;          // not the last group

    // final: sum 128 group partials + 32 elementwise partials (fixed tree)
    __threadfence();
    double acc = gpart[lane] + gpart[64 + lane];
    if (lane < 32) acc += epart[lane];
#pragma unroll
    for (int off = 32; off; off >>= 1)
        acc += __shfl_xor(acc, off, 64);
    if (lane == 0) out[0] = (float)acc;
}

extern "C" void kernel_launch(void* const* d_in, const int* in_sizes, int n_in,
                              void* d_out, int out_size, void* d_ws, size_t ws_size,
                              hipStream_t stream) {
    const float* pos = (const float*)d_in[0];
    const float* scales = (const float*)d_in[1];
    const float* rots = (const float*)d_in[2];
    const float* colors = (const float*)d_in[3];
    int n = in_sizes[0] / 3;  // 8192

    char* ws = (char*)d_ws;
    float4* packed = (float4*)ws;                       ws += (size_t)n * sizeof(float4);
    unsigned* lists = (unsigned*)ws;                    ws += (size_t)16 * n * 32;
    double* epart = (double*)ws;                        ws += 32 * sizeof(double);
    double* gpart = (double*)ws;                        ws += 128 * sizeof(double);
    unsigned* ctrg = (unsigned*)ws;

    prep_kernel<<<n / 256, 256, 0, stream>>>(pos, scales, rots, colors, packed, epart, ctrg, n);
    pass_kernel<<<dim3(n / 64, 16), 256, 0, stream>>>(packed, colors, lists, ctrg, gpart, epart,
                                                      (float*)d_out, n);
}

// Round 4
// 44.505 us; speedup vs baseline: 1.8867x; 1.8867x over previous
//
#include <hip/hip_runtime.h>
#include <math.h>

#define W_POS 0.1f
#define W_SCALE 0.1f
#define W_ROT 0.1f
#define W_COLOR 0.1f

#define CHUNK 512           // candidates per chunk (8 KB LDS stage)
#define NSPLIT 16           // 8192 / CHUNK

__device__ __forceinline__ unsigned umed3(unsigned a, unsigned b, unsigned c) {
    unsigned d;
    asm("v_med3_u32 %0, %1, %2, %3" : "=v"(d) : "v"(a), "v"(b), "v"(c));
    return d;
}
__device__ __forceinline__ unsigned umin_(unsigned a, unsigned b) {
    unsigned d;
    asm("v_min_u32 %0, %1, %2" : "=v"(d) : "v"(a), "v"(b));
    return d;
}

// Insert key into ascending sorted 7-list e0..e6 (drops current max).
// e_k = min(e_k, max(e_{k-1}, key)) == med3(key, e_{k-1}, e_k) since e_{k-1} <= e_k.
// All updates read OLD neighbor values -> 7 independent ops (good ILP).
#define INSERT7(keyv) do { unsigned _k = (keyv);  \
    e6 = umed3(_k, e5, e6);                       \
    e5 = umed3(_k, e4, e5);                       \
    e4 = umed3(_k, e3, e4);                       \
    e3 = umed3(_k, e2, e3);                       \
    e2 = umed3(_k, e1, e2);                       \
    e1 = umed3(_k, e0, e1);                       \
    e0 = umin_(e0, _k);  } while (0)

// Kernel 1: pack positions {x,y,z,|x|^2} + all elementwise losses -> epart[32].
__global__ __launch_bounds__(256) void prep_kernel(
    const float* __restrict__ pos,
    const float* __restrict__ scales,
    const float* __restrict__ rots,
    const float* __restrict__ colors,
    float4* __restrict__ packed,
    double* __restrict__ epart, int n)
{
    const int r = blockIdx.x * 256 + threadIdx.x;

    float x = pos[3 * r], y = pos[3 * r + 1], z = pos[3 * r + 2];
    packed[r] = make_float4(x, y, z, x * x + y * y + z * z);

    const float invn = 1.0f / (float)n;
    float s0 = scales[3 * r], s1 = scales[3 * r + 1], s2 = scales[3 * r + 2];
    float m = (s0 + s1 + s2) * (1.0f / 3.0f);
    float var = ((s0 - m) * (s0 - m) + (s1 - m) * (s1 - m) + (s2 - m) * (s2 - m)) * 0.5f;
    float al = fabsf(s0 - 1.0f) + fabsf(s1 - 1.0f) + fabsf(s2 - 1.0f);
    float r0 = rots[4 * r], r1 = rots[4 * r + 1], r2 = rots[4 * r + 2], r3 = rots[4 * r + 3];
    float nm = sqrtf(r0 * r0 + r1 * r1 + r2 * r2 + r3 * r3);
    float c0 = colors[3 * r], c1 = colors[3 * r + 1], c2 = colors[3 * r + 2];

    float contrib =
        W_SCALE * (al * (invn / 3.0f) + var * invn) +
        W_ROT * (nm - 1.0f) * (nm - 1.0f) * invn +
        W_COLOR * ((c0 - .5f) * (c0 - .5f) + (c1 - .5f) * (c1 - .5f) + (c2 - .5f) * (c2 - .5f)) * (invn / 3.0f);

    __shared__ double sm[256];
    sm[threadIdx.x] = (double)contrib;
    __syncthreads();
    for (int step = 128; step; step >>= 1) {
        if ((int)threadIdx.x < step) sm[threadIdx.x] += sm[threadIdx.x + step];
        __syncthreads();
    }
    if (threadIdx.x == 0) epart[blockIdx.x] = sm[0];
}

// Kernel 2: lane owns a row; block covers 256 rows x one 512-candidate chunk.
// Chunk staged once in LDS (8 KB), read back at wave-uniform addresses
// (HW broadcast, conflict-free). Writes one sorted 7-list per (chunk,row).
__global__ __launch_bounds__(256) void pass_kernel(
    const float4* __restrict__ packed,
    unsigned* __restrict__ lists, int n)
{
    const int lane = threadIdx.x & 63;
    const int wv = threadIdx.x >> 6;
    const int row = blockIdx.x * 256 + wv * 64 + lane;
    const int s = blockIdx.y;

    __shared__ float4 cand[CHUNK];
    const float4* src = packed + s * CHUNK;
    cand[threadIdx.x] = src[threadIdx.x];
    cand[threadIdx.x + 256] = src[threadIdx.x + 256];

    const float4 q = packed[row];
    const float sqi = q.w;
    const float qx2 = -2.0f * q.x, qy2 = -2.0f * q.y, qz2 = -2.0f * q.z;

    unsigned e0 = 0xFFFFFFFFu, e1 = 0xFFFFFFFFu, e2 = 0xFFFFFFFFu, e3 = 0xFFFFFFFFu,
             e4 = 0xFFFFFFFFu, e5 = 0xFFFFFFFFu, e6 = 0xFFFFFFFFu;

    __syncthreads();

    const unsigned jbase = (unsigned)(s * CHUNK);
#pragma unroll 8
    for (int t = 0; t < CHUNK; ++t) {
        float4 p = cand[t];
        float c0 = fmaf(qz2, p.z, sqi);
        float c1 = fmaf(qy2, p.y, c0);
        float c2 = fmaf(qx2, p.x, c1);
        float d2 = fmaxf(c2 + p.w, 0.0f);
        // truncate low 13 mantissa bits, pack candidate index: order matches
        // top_k (distance asc, then smaller index)  ->  v_and_or_b32
        unsigned key = (__float_as_uint(d2) & 0xFFFFE000u) | (jbase + (unsigned)t);
        INSERT7(key);
    }

    unsigned* dst = lists + (((size_t)s * n + row) << 3);
    *(uint4*)dst = make_uint4(e0, e1, e2, e3);
    *(uint4*)(dst + 4) = make_uint4(e4, e5, e6, 0xFFFFFFFFu);
}

// Kernel 3: one thread per row: merge the 16 sorted 7-lists, epilogue terms,
// block-reduce (double) -> bpart[32].
__global__ __launch_bounds__(256) void merge_kernel(
    const float4* __restrict__ packed,
    const unsigned* __restrict__ lists,
    const float* __restrict__ colors,
    double* __restrict__ bpart, int n)
{
    const int r = blockIdx.x * 256 + threadIdx.x;

    unsigned e0 = 0xFFFFFFFFu, e1 = 0xFFFFFFFFu, e2 = 0xFFFFFFFFu, e3 = 0xFFFFFFFFu,
             e4 = 0xFFFFFFFFu, e5 = 0xFFFFFFFFu, e6 = 0xFFFFFFFFu;
#pragma unroll
    for (int s2 = 0; s2 < NSPLIT; ++s2) {
        const uint4* p4 = (const uint4*)(lists + (((size_t)s2 * n + r) << 3));
        uint4 a = p4[0], b = p4[1];
        INSERT7(a.x); INSERT7(a.y); INSERT7(a.z); INSERT7(a.w);
        INSERT7(b.x); INSERT7(b.y); INSERT7(b.z);
    }

    // self-exclusion (self may sit anywhere, or be absent if d2 rounded negative)
    const unsigned M = 0x1FFFu;
    int spos = ((e0 & M) == (unsigned)r) ? 0 :
               ((e1 & M) == (unsigned)r) ? 1 :
               ((e2 & M) == (unsigned)r) ? 2 :
               ((e3 & M) == (unsigned)r) ? 3 :
               ((e4 & M) == (unsigned)r) ? 4 :
               ((e5 & M) == (unsigned)r) ? 5 :
               ((e6 & M) == (unsigned)r) ? 6 : 7;
    unsigned u0 = (spos == 0) ? e1 : e0;
    unsigned u1 = (spos <= 1) ? e2 : e1;
    unsigned u2 = (spos <= 2) ? e3 : e2;
    unsigned u3 = (spos <= 3) ? e4 : e3;
    unsigned u4 = (spos <= 4) ? e5 : e4;

    // exact recompute of 2nd-NN distance (selection keys were truncated)
    const float4 q = packed[r];
    const int i2 = (int)(u1 & M);
    const float4 p2 = packed[i2];
    float dot2 = fmaf(q.x, p2.x, fmaf(q.y, p2.y, q.z * p2.z));
    float d2e = fmaxf(q.w + p2.w - 2.0f * dot2, 0.0f);
    float min_d = sqrtf(d2e);

    // color smoothness over the 5 nearest off-diag neighbors
    float c0 = colors[3 * r], c1 = colors[3 * r + 1], c2 = colors[3 * r + 2];
    float cs = 0.0f;
    unsigned nb[5] = { u0, u1, u2, u3, u4 };
#pragma unroll
    for (int k = 0; k < 5; ++k) {
        int nidx = (int)(nb[k] & M);
        cs += fabsf(c0 - colors[3 * nidx]);
        cs += fabsf(c1 - colors[3 * nidx + 1]);
        cs += fabsf(c2 - colors[3 * nidx + 2]);
    }

    const float invn = 1.0f / (float)n;
    float contrib = cs * (W_COLOR * invn / 15.0f) + expf(-min_d) * (W_POS * invn);

    __shared__ double sm[256];
    sm[threadIdx.x] = (double)contrib;
    __syncthreads();
    for (int step = 128; step; step >>= 1) {
        if ((int)threadIdx.x < step) sm[threadIdx.x] += sm[threadIdx.x + step];
        __syncthreads();
    }
    if (threadIdx.x == 0) bpart[blockIdx.x] = sm[0];
}

// Kernel 4: deterministic final sum of 32 merge partials + 32 elementwise partials.
__global__ void final_kernel(const double* __restrict__ bpart,
                             const double* __restrict__ epart,
                             float* __restrict__ out)
{
    const int lane = threadIdx.x & 63;
    double acc = (lane < 32) ? (bpart[lane] + epart[lane]) : 0.0;
#pragma unroll
    for (int off = 32; off; off >>= 1)
        acc += __shfl_xor(acc, off, 64);
    if (lane == 0) out[0] = (float)acc;
}

extern "C" void kernel_launch(void* const* d_in, const int* in_sizes, int n_in,
                              void* d_out, int out_size, void* d_ws, size_t ws_size,
                              hipStream_t stream) {
    const float* pos = (const float*)d_in[0];
    const float* scales = (const float*)d_in[1];
    const float* rots = (const float*)d_in[2];
    const float* colors = (const float*)d_in[3];
    int n = in_sizes[0] / 3;  // 8192

    char* ws = (char*)d_ws;
    float4* packed = (float4*)ws;                 ws += (size_t)n * sizeof(float4);
    unsigned* lists = (unsigned*)ws;              ws += (size_t)NSPLIT * n * 32;
    double* epart = (double*)ws;                  ws += 32 * sizeof(double);
    double* bpart = (double*)ws;

    prep_kernel<<<n / 256, 256, 0, stream>>>(pos, scales, rots, colors, packed, epart, n);
    pass_kernel<<<dim3(n / 256, NSPLIT), 256, 0, stream>>>(packed, lists, n);
    merge_kernel<<<n / 256, 256, 0, stream>>>(packed, lists, colors, bpart, n);
    final_kernel<<<1, 64, 0, stream>>>(bpart, epart, (float*)d_out);
}